// Round 11
// baseline (439.256 us; speedup 1.0000x reference)
//
#include <hip/hip_runtime.h>
#include <hip/hip_bf16.h>

// GraphSAINT 2-layer GCN forward on MI355X.
// Layer 1: xs[n] = bf16(dis[n]*x[n]);  zb[d] = bf16(dis[d]*(sum_e xs[s] + xs[d]));
//          out1b = bf16(zb @ W1 + b1)   (bf16 MFMA; BN partials fused).
// Layer 2: gs[n] = bf16(dis[n]*(relu(bn(out1b[n])) @ W2))  (bf16 MFMA);
//          out[d] = dis[d]*(sum_e gs[s] + gs[d]) + b2  (fp32).
// R26: edge bucketing rebuilt as atomic-free count/scan/scatter.  R25 profile
// showed scatter_wprep at 41 us with VALUBusy 1.4% -- the contended global
// atomicAdd-with-return on bcursor (196-deep same-address RMW chains x ~200ns
// cross-XCD = ~39 us) was the serializer.  Now: S1 counts per (chunk,bucket)
// with plain stores; S2 single-block exclusive scan (76,636 cells) gives
// deterministic bases and a PACKED ebuf; S3 scatters with per-block-exclusive
// LDS cursors.  No global RMW anywhere in the sort.  BK_SIZE reverted to 256
// (R25's 128 change was implicated in the +15 us regression); aggx keeps the
// two-dispatch split (visibility, neutral).  gemm1/bnred/gemm2/agg2 and
// bucket_build body byte-identical to the measured R24 build (312.4 us).

#define IN_F  128
#define HID_F 256
#define OUT_F 64
#define BK_SHIFT 8
#define BK_SIZE  256
#define CHUNK    8192
#define CAP      8192   // per-bucket ssrc capacity (mean 4092, sigma ~64)

typedef unsigned int uint;
typedef unsigned short ushort;
typedef short bf16x8 __attribute__((ext_vector_type(8)));
typedef float f32x4 __attribute__((ext_vector_type(4)));

__device__ __forceinline__ ushort f2bf(float f) {
    uint u = __float_as_uint(f);
    uint r = (u + 0x7fffu + ((u >> 16) & 1u)) >> 16;  // RNE
    return (ushort)r;
}
__device__ __forceinline__ float bf_lo(uint u) { return __uint_as_float(u << 16); }
__device__ __forceinline__ float bf_hi(uint u) { return __uint_as_float(u & 0xffff0000u); }

#define ACC8(u)                                         \
    do {                                                \
        acc[0] += bf_lo((u).x); acc[1] += bf_hi((u).x); \
        acc[2] += bf_lo((u).y); acc[3] += bf_hi((u).y); \
        acc[4] += bf_lo((u).z); acc[5] += bf_hi((u).z); \
        acc[6] += bf_lo((u).w); acc[7] += bf_hi((u).w); \
    } while (0)

// --- sort pipeline (atomic-free count/scan/scatter) --------------------------

// S1: blocks [0,nchunk) histogram their chunk into LDS, then plain-store
// cnts[bucket * nchunk + chunk].  Blocks [nchunk, nchunk+96): W1/W2 repack.
__global__ __launch_bounds__(512) void count_wprep_kernel(
        const int* __restrict__ dst, int* __restrict__ cnts,
        const float* __restrict__ W1, const float* __restrict__ W2,
        ushort* __restrict__ W1bp, ushort* __restrict__ W2bp,
        int E, int NB, int nchunk) {
    if (blockIdx.x >= nchunk) {
        int i = (blockIdx.x - nchunk) * 512 + threadIdx.x;  // 49152 total
        if (i < 32768) {
            int kk = i & 31, c = (i >> 5) & 255, kc = i >> 13;
            W1bp[i] = f2bf(W1[(size_t)(kc * 32 + kk) * HID_F + c]);
        } else {
            int j = i - 32768;
            int kk = j & 31, c = (j >> 5) & 63, kc = j >> 11;
            W2bp[j] = f2bf(W2[(size_t)(kc * 32 + kk) * OUT_F + c]);
        }
        return;
    }
    __shared__ int h[512];
    for (int i = threadIdx.x; i < NB; i += 512) h[i] = 0;
    __syncthreads();
    int c = blockIdx.x;
    int base = c * CHUNK;
    int end = min(base + CHUNK, E);
    for (int i = base + threadIdx.x; i < end; i += 512)
        atomicAdd(&h[dst[i] >> BK_SHIFT], 1);
    __syncthreads();
    for (int i = threadIdx.x; i < NB; i += 512)
        cnts[(size_t)i * nchunk + c] = h[i];
}

// S2: exclusive scan over M = NB*nchunk cells (bucket-major) + sentinel.
// Single block, 1024 threads, ~75 cells/thread.
__global__ __launch_bounds__(1024) void scan_kernel(const int* __restrict__ cnts,
                                                    int* __restrict__ bases, int M) {
    __shared__ int part[1024];
    int t = threadIdx.x;
    int per = (M + 1023) >> 10;
    int lo = t * per, hi = min(lo + per, M);
    int s = 0;
    for (int k = lo; k < hi; k++) s += cnts[k];
    part[t] = s;
    __syncthreads();
    for (int o = 1; o < 1024; o <<= 1) {
        int u = (t >= o) ? part[t - o] : 0;
        __syncthreads();
        part[t] += u;
        __syncthreads();
    }
    int run = (t == 0) ? 0 : part[t - 1];
    for (int k = lo; k < hi; k++) { int v = cnts[k]; bases[k] = run; run += v; }
    if (t == 1023) bases[M] = run;  // == E
}

// S3: scatter with per-block-exclusive LDS cursors seeded from bases.
__global__ __launch_bounds__(512) void scatter_kernel(
        const int* __restrict__ src, const int* __restrict__ dst,
        const int* __restrict__ bases, uint* __restrict__ ebuf,
        int E, int NB, int nchunk) {
    __shared__ int cur[512];
    int c = blockIdx.x;
    for (int i = threadIdx.x; i < NB; i += 512)
        cur[i] = bases[(size_t)i * nchunk + c];
    __syncthreads();
    int base = c * CHUNK;
    int end = min(base + CHUNK, E);
    for (int i = base + threadIdx.x; i < end; i += 512) {
        int d = dst[i], s = src[i];
        int b = d >> BK_SHIFT;
        int pos = atomicAdd(&cur[b], 1);
        ebuf[pos] = (uint)s | ((uint)(d & (BK_SIZE - 1)) << 24);
    }
}

// One block (1024 threads) per bucket of 256 nodes: LDS count/scan/sort.
// Pads each node's edge list to a multiple of 4 with sentinel src = N.
// Fused xprep tail: block b writes xs rows for its 256 nodes.
__global__ __launch_bounds__(1024) void bucket_build_kernel(
        const uint* __restrict__ ebuf, const int* __restrict__ bases,
        int* __restrict__ deg_e, int* __restrict__ offsets,
        float* __restrict__ dis, int* __restrict__ ssrc,
        const float* __restrict__ x, uint* __restrict__ xs, int N, int nchunk) {
    __shared__ int cnt[256], off[256], cur[256];
    __shared__ float sdis[256];
    int b = blockIdx.x;
    int t = threadIdx.x;
    if (t < 256) cnt[t] = 0;
    __syncthreads();
    int e0 = bases[(size_t)b * nchunk];
    int e1 = bases[(size_t)(b + 1) * nchunk];   // sentinel at M covers b==NB-1
    for (int i = e0 + t; i < e1; i += 1024)
        atomicAdd(&cnt[ebuf[i] >> 24], 1);
    __syncthreads();
    int v = (t < 256) ? cnt[t] : 0;
    int vpad = (v + 3) & ~3;
    if (t < 256) off[t] = vpad;
    __syncthreads();
    for (int o = 1; o < 256; o <<= 1) {
        int u = (t >= o && t < 256) ? off[t - o] : 0;
        __syncthreads();
        if (t < 256) off[t] += u;
        __syncthreads();
    }
    int base_pad = b * (CAP + 768);
    if (t < 256) {
        int excl = off[t] - vpad;
        int d = b * BK_SIZE + t;
        float dv = rsqrtf((float)(v + 1));
        sdis[t] = dv;
        if (d < N) {
            deg_e[d] = vpad;
            offsets[d] = base_pad + excl;
            dis[d] = dv;
        }
        cur[t] = excl;
    }
    __syncthreads();
    for (int i = e0 + t; i < e1; i += 1024) {
        uint e = ebuf[i];
        int ld = e >> 24;
        int pos = atomicAdd(&cur[ld], 1);
        ssrc[base_pad + pos] = (int)(e & 0xFFFFFFu);
    }
    __syncthreads();
    if (t < 256) {
        int excl = off[t] - vpad;
        for (int i = v; i < vpad; i++)
            ssrc[base_pad + excl + i] = N;
    }
    // fused xprep: 256 nodes x 32 uint2 (4 floats each) = 8192 items
    for (int i = t; i < 256 * 32; i += 1024) {
        int nl = i >> 5;                // node within bucket
        int w = i & 31;                 // uint2 within row
        int d = b * BK_SIZE + nl;
        if (d > N) continue;
        size_t oi = (size_t)d * 32 + w;
        if (d == N) { ((uint2*)xs)[oi] = make_uint2(0u, 0u); continue; }
        float dn = sdis[nl];
        float4 vv = ((const float4*)x)[oi];
        uint2 o;
        o.x = (uint)f2bf(dn * vv.x) | ((uint)f2bf(dn * vv.y) << 16);
        o.y = (uint)f2bf(dn * vv.z) | ((uint)f2bf(dn * vv.w) << 16);
        ((uint2*)xs)[oi] = o;
    }
}

// --- compute pipeline --------------------------------------------------------

// zb[d] = bf16(dis[d]*(sum_e xs[s] + xs[d])).  2 nodes/wave (32-lane halves;
// 4 groups x 8 lanes; 4-edge rounds match pad-4).  Feature half selected by
// bit 2 of blockIdx&7 (XCD round-robin).  oct0 = base node-octet.
__global__ void aggx_kernel(const uint* __restrict__ xs, const int* __restrict__ ssrc,
                            const int* __restrict__ offsets, const int* __restrict__ deg_e,
                            const float* __restrict__ dis, uint* __restrict__ zb,
                            int oct0, int N) {
    int lane = threadIdx.x & 63;
    int half = lane >> 5;
    int hl = lane & 31;
    int grp = hl >> 3;
    int ck = hl & 7;
    int j = blockIdx.x & 7;                        // XCD (empirical mapping)
    int fo = (j >> 2) << 5;                        // feature-half offset in uints
    int oct = oct0 + ((blockIdx.x >> 3) << 2) + (j & 3);  // node octet index
    int n = (oct << 3) + ((threadIdx.x >> 6) << 1) + half;
    if (n >= N) return;
    float acc[8];
#pragma unroll
    for (int i = 0; i < 8; i++) acc[i] = 0.f;
    int start = offsets[n], cnt = deg_e[n];  // cnt % 4 == 0
    uint4 uself = *(const uint4*)(xs + ((size_t)n << 6) + fo + (ck << 2));  // prefetch self
    int hbase = half << 5;
    for (int base = 0; base < cnt; base += 32) {
        int m = min(32, cnt - base);
        int idx = base + hl;
        int sv = ssrc[start + (idx < cnt ? idx : cnt - 1)];
        int rounds = m >> 2;  // 1..8
        int q = 0;
        for (; q + 4 <= rounds; q += 4) {
            int sA = __shfl(sv, hbase | ((q + 0) << 2) | grp);
            int sB = __shfl(sv, hbase | ((q + 1) << 2) | grp);
            int sC = __shfl(sv, hbase | ((q + 2) << 2) | grp);
            int sD = __shfl(sv, hbase | ((q + 3) << 2) | grp);
            uint4 uA = *(const uint4*)(xs + ((size_t)sA << 6) + fo + (ck << 2));
            uint4 uB = *(const uint4*)(xs + ((size_t)sB << 6) + fo + (ck << 2));
            uint4 uC = *(const uint4*)(xs + ((size_t)sC << 6) + fo + (ck << 2));
            uint4 uD = *(const uint4*)(xs + ((size_t)sD << 6) + fo + (ck << 2));
            ACC8(uA); ACC8(uB); ACC8(uC); ACC8(uD);
        }
        for (; q < rounds; q++) {
            int s = __shfl(sv, hbase | (q << 2) | grp);
            uint4 u = *(const uint4*)(xs + ((size_t)s << 6) + fo + (ck << 2));
            ACC8(u);
        }
    }
#pragma unroll
    for (int i = 0; i < 8; i++) acc[i] += __shfl_down(acc[i], 16);
#pragma unroll
    for (int i = 0; i < 8; i++) acc[i] += __shfl_down(acc[i], 8);
    if (grp == 0) {
        ACC8(uself);  // self-loop term
        float dn = dis[n];
        uint4 o;
        o.x = (uint)f2bf(dn * acc[0]) | ((uint)f2bf(dn * acc[1]) << 16);
        o.y = (uint)f2bf(dn * acc[2]) | ((uint)f2bf(dn * acc[3]) << 16);
        o.z = (uint)f2bf(dn * acc[4]) | ((uint)f2bf(dn * acc[5]) << 16);
        o.w = (uint)f2bf(dn * acc[6]) | ((uint)f2bf(dn * acc[7]) << 16);
        *(uint4*)(zb + ((size_t)n << 6) + fo + (ck << 2)) = o;
    }
}

// out1b = bf16(zb @ W1 + b1) + per-block BN partials.
__global__ __launch_bounds__(256) void gemm1_kernel(const uint* __restrict__ zb,
                                                    const uint* __restrict__ W1bp,
                                                    const float* __restrict__ b1,
                                                    ushort* __restrict__ out1b,
                                                    float* __restrict__ bnp, int N) {
    __shared__ uint sbuf[8192];  // A tile (16 KB) then C staging (32 KB)
    int t = threadIdx.x;
    int n0 = blockIdx.x * 64;
    for (int i = t; i < 64 * 16; i += 256) {
        int r = i >> 4, q = i & 15;
        int node = n0 + r;
        uint4 v = make_uint4(0u, 0u, 0u, 0u);
        if (node < N) v = *(const uint4*)(zb + (size_t)node * 64 + q * 4);
        int p = q ^ (r & 15);  // XOR swizzle: conflict-free b128
        *(uint4*)(&sbuf[r * 64 + p * 4]) = v;
    }
    __syncthreads();
    int wave = t >> 6, lane = t & 63;
    int quad = lane >> 4, lrow = lane & 15;
    f32x4 acc[4][4];
#pragma unroll
    for (int m = 0; m < 4; m++)
#pragma unroll
        for (int nt = 0; nt < 4; nt++) acc[m][nt] = (f32x4)(0.f);
#pragma unroll
    for (int kc = 0; kc < 4; kc++) {
        bf16x8 bfr[4];
#pragma unroll
        for (int nt = 0; nt < 4; nt++) {
            int c = wave * 64 + nt * 16 + lrow;
            bfr[nt] = *(const bf16x8*)(W1bp + ((size_t)(kc * 256 + c) * 16 + quad * 4));
        }
        bf16x8 afr[4];
#pragma unroll
        for (int m = 0; m < 4; m++) {
            int p = (kc * 4 + quad) ^ lrow;
            afr[m] = *(const bf16x8*)(&sbuf[(m * 16 + lrow) * 64 + p * 4]);
        }
#pragma unroll
        for (int m = 0; m < 4; m++)
#pragma unroll
            for (int nt = 0; nt < 4; nt++)
                acc[m][nt] = __builtin_amdgcn_mfma_f32_16x16x32_bf16(
                    afr[m], bfr[nt], acc[m][nt], 0, 0, 0);
    }
    __syncthreads();  // A reads done; reuse sbuf for C staging
#pragma unroll
    for (int nt = 0; nt < 4; nt++) {
        int c = wave * 64 + nt * 16 + lrow;
        float bb = b1[c];
        float s = 0.f, q = 0.f;
#pragma unroll
        for (int m = 0; m < 4; m++) {
#pragma unroll
            for (int r = 0; r < 4; r++) {
                int row = m * 16 + quad * 4 + r;
                float v = acc[m][nt][r] + bb;
                if (n0 + row < N) { s += v; q = fmaf(v, v, q); }
                uint hv = (uint)f2bf(v);
                uint pv = __shfl_xor(hv, 1);
                if ((lrow & 1) == 0)
                    sbuf[row * 128 + (c >> 1)] = hv | (pv << 16);
            }
        }
        s += __shfl_down(s, 32); q += __shfl_down(q, 32);
        s += __shfl_down(s, 16); q += __shfl_down(q, 16);
        if (quad == 0) {
            bnp[(size_t)blockIdx.x * 512 + c] = s;
            bnp[(size_t)blockIdx.x * 512 + 256 + c] = q;
        }
    }
    __syncthreads();
    uint* out1g = (uint*)out1b;
    for (int i = t; i < 2048; i += 256) {  // 64 rows x 32 uint4
        int row = i >> 5;
        if (n0 + row < N)
            *(uint4*)(out1g + (size_t)(n0 + row) * 128 + (i & 31) * 4) =
                *(const uint4*)(&sbuf[i * 4]);
    }
}

// Single-stage BN partial reduce: 32 blocks, atomic-add final sums (zeroed).
__global__ void bnred_kernel(const float* __restrict__ bnp, float* __restrict__ bnsum,
                             int nblk) {
    int g = blockIdx.x, t = threadIdx.x;
    float s = 0.f, q = 0.f;
    for (int b = g; b < nblk; b += 32) {
        s += bnp[(size_t)b * 512 + t];
        q += bnp[(size_t)b * 512 + 256 + t];
    }
    atomicAdd(&bnsum[t], s);
    atomicAdd(&bnsum[256 + t], q);
}

// gs = bf16(dis * (relu(bn(out1b)) @ W2)); scale/bias computed in prologue.
__global__ __launch_bounds__(256) void gemm2_kernel(const ushort* __restrict__ out1b,
                                                    const uint* __restrict__ W2bp,
                                                    const float* __restrict__ dis,
                                                    const float* __restrict__ bnsum,
                                                    const float* __restrict__ gamma,
                                                    const float* __restrict__ beta,
                                                    ushort* __restrict__ gs, int N) {
    __shared__ uint sbuf[8192];
    __shared__ float bns[256], bnb[256];
    const uint* out1u = (const uint*)out1b;
    int t = threadIdx.x;
    int n0 = blockIdx.x * 64;
    if (blockIdx.x == 0 && t < 32) ((uint*)gs)[(size_t)N * 32 + t] = 0u;  // sentinel row
    {
        float invN = 1.0f / (float)N;
        float mean = bnsum[t] * invN;
        float var = bnsum[256 + t] * invN - mean * mean;
        float sc = gamma[t] * rsqrtf(fmaxf(var, 0.f) + 1e-5f);
        bns[t] = sc;
        bnb[t] = beta[t] - mean * sc;
    }
    __syncthreads();
    for (int i = t; i < 64 * 32; i += 256) {
        int r = i >> 5, q = i & 31;
        int node = n0 + r;
        uint4 v = make_uint4(0u, 0u, 0u, 0u);
        if (node < N) {
            uint4 w = *(const uint4*)(out1u + (size_t)node * 128 + q * 4);
            int c0 = q * 8;
            float r0 = fmaxf(fmaf(bf_lo(w.x), bns[c0 + 0], bnb[c0 + 0]), 0.f);
            float r1 = fmaxf(fmaf(bf_hi(w.x), bns[c0 + 1], bnb[c0 + 1]), 0.f);
            float r2 = fmaxf(fmaf(bf_lo(w.y), bns[c0 + 2], bnb[c0 + 2]), 0.f);
            float r3 = fmaxf(fmaf(bf_hi(w.y), bns[c0 + 3], bnb[c0 + 3]), 0.f);
            float r4 = fmaxf(fmaf(bf_lo(w.z), bns[c0 + 4], bnb[c0 + 4]), 0.f);
            float r5 = fmaxf(fmaf(bf_hi(w.z), bns[c0 + 5], bnb[c0 + 5]), 0.f);
            float r6 = fmaxf(fmaf(bf_lo(w.w), bns[c0 + 6], bnb[c0 + 6]), 0.f);
            float r7 = fmaxf(fmaf(bf_hi(w.w), bns[c0 + 7], bnb[c0 + 7]), 0.f);
            v.x = (uint)f2bf(r0) | ((uint)f2bf(r1) << 16);
            v.y = (uint)f2bf(r2) | ((uint)f2bf(r3) << 16);
            v.z = (uint)f2bf(r4) | ((uint)f2bf(r5) << 16);
            v.w = (uint)f2bf(r6) | ((uint)f2bf(r7) << 16);
        }
        int p = (q & 16) | ((q & 15) ^ (r & 15));  // XOR swizzle (low 4 bits)
        *(uint4*)(&sbuf[r * 128 + p * 4]) = v;
    }
    __syncthreads();
    int wave = t >> 6, lane = t & 63;
    int quad = lane >> 4, lrow = lane & 15;
    int c = wave * 16 + lrow;
    f32x4 acc[4];
#pragma unroll
    for (int m = 0; m < 4; m++) acc[m] = (f32x4)(0.f);
#pragma unroll
    for (int kc = 0; kc < 8; kc++) {
        bf16x8 bfr = *(const bf16x8*)(W2bp + ((size_t)(kc * 64 + c) * 16 + quad * 4));
#pragma unroll
        for (int m = 0; m < 4; m++) {
            int q = kc * 4 + quad;
            int p = (q & 16) | ((q & 15) ^ lrow);
            bf16x8 afr = *(const bf16x8*)(&sbuf[(m * 16 + lrow) * 128 + p * 4]);
            acc[m] = __builtin_amdgcn_mfma_f32_16x16x32_bf16(afr, bfr, acc[m], 0, 0, 0);
        }
    }
    __syncthreads();
#pragma unroll
    for (int m = 0; m < 4; m++) {
#pragma unroll
        for (int r = 0; r < 4; r++) {
            int row = m * 16 + quad * 4 + r;
            int node = n0 + row;
            float dn = (node < N) ? dis[node] : 0.f;
            uint hv = (uint)f2bf(dn * acc[m][r]);
            uint pv = __shfl_xor(hv, 1);
            if ((lrow & 1) == 0)
                sbuf[row * 32 + (c >> 1)] = hv | (pv << 16);
        }
    }
    __syncthreads();
    uint* gsg = (uint*)gs;
    for (int i = t; i < 512; i += 256) {
        int row = i >> 3;
        if (n0 + row < N)
            *(uint4*)(gsg + (size_t)(n0 + row) * 32 + (i & 7) * 4) =
                *(const uint4*)(&sbuf[i * 4]);
    }
}

// out[d] = dis[d]*(sum_e gs[s] + gs[d]) + b2.  2 nodes per wave (32-lane
// halves); 4 groups x 8 lanes per half; 4 edges/round (matches pad-4).
// 4-deep batched gathers + self-row prefetch.
__global__ void agg2_kernel(const uint* __restrict__ gs, const int* __restrict__ ssrc,
                            const int* __restrict__ offsets, const int* __restrict__ deg_e,
                            const float* __restrict__ dis, const float* __restrict__ b2,
                            float* __restrict__ out, int N) {
    int lane = threadIdx.x & 63;
    int half = lane >> 5;
    int hl = lane & 31;
    int grp = hl >> 3;
    int ck = hl & 7;
    int n = blockIdx.x * 8 + ((threadIdx.x >> 6) << 1) + half;
    if (n >= N) return;
    float acc[8];
#pragma unroll
    for (int i = 0; i < 8; i++) acc[i] = 0.f;
    int start = offsets[n], cnt = deg_e[n];  // cnt % 4 == 0
    uint4 uself = *(const uint4*)(gs + ((size_t)n << 5) + (ck << 2));  // prefetch self
    int hbase = half << 5;
    for (int base = 0; base < cnt; base += 32) {
        int m = min(32, cnt - base);
        int idx = base + hl;
        int sv = ssrc[start + (idx < cnt ? idx : cnt - 1)];
        int rounds = m >> 2;  // 1..8
        int q = 0;
        for (; q + 4 <= rounds; q += 4) {
            int sA = __shfl(sv, hbase | ((q + 0) << 2) | grp);
            int sB = __shfl(sv, hbase | ((q + 1) << 2) | grp);
            int sC = __shfl(sv, hbase | ((q + 2) << 2) | grp);
            int sD = __shfl(sv, hbase | ((q + 3) << 2) | grp);
            uint4 uA = *(const uint4*)(gs + ((size_t)sA << 5) + (ck << 2));
            uint4 uB = *(const uint4*)(gs + ((size_t)sB << 5) + (ck << 2));
            uint4 uC = *(const uint4*)(gs + ((size_t)sC << 5) + (ck << 2));
            uint4 uD = *(const uint4*)(gs + ((size_t)sD << 5) + (ck << 2));
            ACC8(uA); ACC8(uB); ACC8(uC); ACC8(uD);
        }
        for (; q + 2 <= rounds; q += 2) {
            int sA = __shfl(sv, hbase | ((q + 0) << 2) | grp);
            int sB = __shfl(sv, hbase | ((q + 1) << 2) | grp);
            uint4 uA = *(const uint4*)(gs + ((size_t)sA << 5) + (ck << 2));
            uint4 uB = *(const uint4*)(gs + ((size_t)sB << 5) + (ck << 2));
            ACC8(uA); ACC8(uB);
        }
        for (; q < rounds; q++) {
            int s = __shfl(sv, hbase | (q << 2) | grp);
            uint4 u = *(const uint4*)(gs + ((size_t)s << 5) + (ck << 2));
            ACC8(u);
        }
    }
#pragma unroll
    for (int i = 0; i < 8; i++) acc[i] += __shfl_down(acc[i], 16);
#pragma unroll
    for (int i = 0; i < 8; i++) acc[i] += __shfl_down(acc[i], 8);
    if (grp == 0) {
        ACC8(uself);  // self-loop term
        float dn = dis[n];
        float4 bb0 = *(const float4*)(b2 + ck * 8);
        float4 bb1 = *(const float4*)(b2 + ck * 8 + 4);
        float* op = out + (size_t)n * OUT_F + ck * 8;
        *(float4*)op = make_float4(fmaf(dn, acc[0], bb0.x), fmaf(dn, acc[1], bb0.y),
                                   fmaf(dn, acc[2], bb0.z), fmaf(dn, acc[3], bb0.w));
        *(float4*)(op + 4) = make_float4(fmaf(dn, acc[4], bb1.x), fmaf(dn, acc[5], bb1.y),
                                         fmaf(dn, acc[6], bb1.z), fmaf(dn, acc[7], bb1.w));
    }
}

extern "C" void kernel_launch(void* const* d_in, const int* in_sizes, int n_in,
                              void* d_out, int out_size, void* d_ws, size_t ws_size,
                              hipStream_t stream) {
    const float* x      = (const float*)d_in[0];
    const int*   edges  = (const int*)d_in[1];
    const float* W1     = (const float*)d_in[2];
    const float* b1     = (const float*)d_in[3];
    const float* gamma1 = (const float*)d_in[4];
    const float* beta1  = (const float*)d_in[5];
    const float* W2     = (const float*)d_in[6];
    const float* b2     = (const float*)d_in[7];
    float* out = (float*)d_out;

    int N = in_sizes[0] / IN_F;
    int E = in_sizes[1] / 2;
    const int* src = edges;
    const int* dst = edges + E;
    int NB = (N + BK_SIZE - 1) / BK_SIZE;   // 391
    int nchunks = (E + CHUNK - 1) / CHUNK;  // 196
    int M = NB * nchunks;                   // 76,636 cells
    int nblk1 = (N + 63) / 64;

    char* ws = (char*)d_ws;
    size_t off = 0;
    auto alloc = [&](size_t bytes) -> void* {
        void* p = ws + off;
        off += (bytes + 255) & ~(size_t)255;
        return p;
    };
    int*    deg_e   = (int*)alloc((size_t)N * 4);
    int*    offsets = (int*)alloc((size_t)N * 4);
    float*  dis     = (float*)alloc((size_t)(N + 1) * 4);
    float*  bnsum   = (float*)alloc(512 * 4);   // sums | sumsq (zeroed)
    int*    cnts    = (int*)alloc((size_t)M * 4);
    int*    bases   = (int*)alloc((size_t)(M + 1) * 4);
    int*    ssrc    = (int*)alloc((size_t)NB * (CAP + 768) * 4);  // padded CSR
    uint*   ebuf    = (uint*)alloc((size_t)E * 4);                // packed
    uint*   xs      = (uint*)alloc((size_t)(N + 1) * (IN_F / 2) * 4); // +sentinel row
    uint*   zb      = (uint*)alloc((size_t)N * (IN_F / 2) * 4);
    ushort* out1b   = (ushort*)alloc((size_t)N * HID_F * 2);
    float*  bnp     = (float*)alloc((size_t)nblk1 * 512 * 4);         // block partials
    ushort* W1bp    = (ushort*)alloc(4 * 256 * 32 * 2);
    ushort* W2bp    = (ushort*)alloc(8 * 64 * 32 * 2);
    ushort* gs      = (ushort*)zb;  // alias: zb dead after gemm1; (N+1) rows x 64 bf16

    hipMemsetAsync(bnsum, 0, 512 * 4, stream);

    count_wprep_kernel<<<nchunks + 96, 512, 0, stream>>>(dst, cnts, W1, W2, W1bp, W2bp,
                                                         E, NB, nchunks);
    scan_kernel<<<1, 1024, 0, stream>>>(cnts, bases, M);
    scatter_kernel<<<nchunks, 512, 0, stream>>>(src, dst, bases, ebuf, E, NB, nchunks);
    bucket_build_kernel<<<NB, 1024, 0, stream>>>(ebuf, bases, deg_e, offsets, dis, ssrc,
                                                 x, xs, N, nchunks);
    {
        int noct = (N + 7) >> 3;                  // 12500 node octets
        int h0 = ((noct / 2 + 3) >> 2) << 2;      // 6252 (multiple of 4)
        int h1 = noct - h0;                       // 6248
        int grid0 = (h0 >> 2) << 3;               // 2 feature halves x 4 octets / 8 blocks
        int grid1 = ((h1 + 3) >> 2) << 3;
        aggx_kernel<<<grid0, 256, 0, stream>>>(xs, ssrc, offsets, deg_e, dis, zb, 0, N);
        aggx_kernel<<<grid1, 256, 0, stream>>>(xs, ssrc, offsets, deg_e, dis, zb, h0, N);
    }
    gemm1_kernel<<<nblk1, 256, 0, stream>>>(zb, (const uint*)W1bp, b1, out1b, bnp, N);
    bnred_kernel<<<32, 256, 0, stream>>>(bnp, bnsum, nblk1);
    gemm2_kernel<<<nblk1, 256, 0, stream>>>(out1b, (const uint*)W2bp, dis, bnsum,
                                            gamma1, beta1, gs, N);
    agg2_kernel<<<(N + 7) / 8, 256, 0, stream>>>((const uint*)gs, ssrc, offsets, deg_e, dis,
                                                 b2, out, N);
}

// Round 12
// 327.527 us; speedup vs baseline: 1.3411x; 1.3411x over previous
//
#include <hip/hip_runtime.h>
#include <hip/hip_bf16.h>

// GraphSAINT 2-layer GCN forward on MI355X.
// Layer 1: xs[n] = bf16(dis[n]*x[n]);  zb[d] = bf16(dis[d]*(sum_e xs[s] + xs[d]));
//          out1b = bf16(zb @ W1 + b1)   (bf16 MFMA; BN partials fused).
// Layer 2: gs[n] = bf16(dis[n]*(relu(bn(out1b[n])) @ W2))  (bf16 MFMA);
//          out[d] = dis[d]*(sum_e gs[s] + gs[d]) + b2  (fp32).
// R27: R26's 121-us single-block scan (0.15% occupancy, latency-serial)
// replaced by a hierarchical scheme with NO serial stage: S2a = 391-block
// per-bucket exclusive scan (local[] + tot[b]); the 391-entry top-level scan
// is folded into scatter_kernel and bucket_build_kernel prologues as a
// 512-wide LDS scan of tot[] (no extra launch).  Sort remains atomic-free
// (R25 profile: contended bcursor RMW chains were 41 us).  All compute
// kernels byte-identical to the measured R24 build (312.4 us).

#define IN_F  128
#define HID_F 256
#define OUT_F 64
#define BK_SHIFT 8
#define BK_SIZE  256
#define CHUNK    8192
#define CAP      8192   // per-bucket ssrc capacity (mean 4092, sigma ~64)

typedef unsigned int uint;
typedef unsigned short ushort;
typedef short bf16x8 __attribute__((ext_vector_type(8)));
typedef float f32x4 __attribute__((ext_vector_type(4)));

__device__ __forceinline__ ushort f2bf(float f) {
    uint u = __float_as_uint(f);
    uint r = (u + 0x7fffu + ((u >> 16) & 1u)) >> 16;  // RNE
    return (ushort)r;
}
__device__ __forceinline__ float bf_lo(uint u) { return __uint_as_float(u << 16); }
__device__ __forceinline__ float bf_hi(uint u) { return __uint_as_float(u & 0xffff0000u); }

#define ACC8(u)                                         \
    do {                                                \
        acc[0] += bf_lo((u).x); acc[1] += bf_hi((u).x); \
        acc[2] += bf_lo((u).y); acc[3] += bf_hi((u).y); \
        acc[4] += bf_lo((u).z); acc[5] += bf_hi((u).z); \
        acc[6] += bf_lo((u).w); acc[7] += bf_hi((u).w); \
    } while (0)

// --- sort pipeline (atomic-free count/scan/scatter, hierarchical scan) -------

// S1: blocks [0,nchunk) histogram their chunk into LDS, then plain-store
// cnts[bucket * nchunk + chunk].  Blocks [nchunk, nchunk+96): W1/W2 repack.
__global__ __launch_bounds__(512) void count_wprep_kernel(
        const int* __restrict__ dst, int* __restrict__ cnts,
        const float* __restrict__ W1, const float* __restrict__ W2,
        ushort* __restrict__ W1bp, ushort* __restrict__ W2bp,
        int E, int NB, int nchunk) {
    if (blockIdx.x >= nchunk) {
        int i = (blockIdx.x - nchunk) * 512 + threadIdx.x;  // 49152 total
        if (i < 32768) {
            int kk = i & 31, c = (i >> 5) & 255, kc = i >> 13;
            W1bp[i] = f2bf(W1[(size_t)(kc * 32 + kk) * HID_F + c]);
        } else {
            int j = i - 32768;
            int kk = j & 31, c = (j >> 5) & 63, kc = j >> 11;
            W2bp[j] = f2bf(W2[(size_t)(kc * 32 + kk) * OUT_F + c]);
        }
        return;
    }
    __shared__ int h[512];
    for (int i = threadIdx.x; i < NB; i += 512) h[i] = 0;
    __syncthreads();
    int c = blockIdx.x;
    int base = c * CHUNK;
    int end = min(base + CHUNK, E);
    for (int i = base + threadIdx.x; i < end; i += 512)
        atomicAdd(&h[dst[i] >> BK_SHIFT], 1);
    __syncthreads();
    for (int i = threadIdx.x; i < NB; i += 512)
        cnts[(size_t)i * nchunk + c] = h[i];
}

// S2a: one block per bucket -- exclusive scan over its nchunk cells (LDS),
// writes local[] (within-bucket exclusive offsets) and tot[b].
// Requires nchunk <= 256.
__global__ __launch_bounds__(256) void scan_bucket_kernel(
        const int* __restrict__ cnts, int* __restrict__ local,
        int* __restrict__ tot, int nchunk) {
    __shared__ int s[256];
    int b = blockIdx.x;
    int t = threadIdx.x;
    int v = (t < nchunk) ? cnts[(size_t)b * nchunk + t] : 0;
    s[t] = v;
    __syncthreads();
    for (int o = 1; o < 256; o <<= 1) {
        int u = (t >= o) ? s[t - o] : 0;
        __syncthreads();
        s[t] += u;
        __syncthreads();
    }
    if (t < nchunk) local[(size_t)b * nchunk + t] = s[t] - v;  // exclusive
    if (t == 255) tot[b] = s[255];
}

// S3: scatter with per-block-exclusive LDS cursors.  Top-level bucket base
// boff[b] computed in-block via 512-wide LDS scan of tot (NB <= 512).
__global__ __launch_bounds__(512) void scatter_kernel(
        const int* __restrict__ src, const int* __restrict__ dst,
        const int* __restrict__ local, const int* __restrict__ tot,
        uint* __restrict__ ebuf, int E, int NB, int nchunk) {
    __shared__ int sb[512];
    __shared__ int cur[512];
    int c = blockIdx.x;
    int t = threadIdx.x;
    int v = (t < NB) ? tot[t] : 0;
    sb[t] = v;
    __syncthreads();
    for (int o = 1; o < 512; o <<= 1) {
        int u = (t >= o) ? sb[t - o] : 0;
        __syncthreads();
        sb[t] += u;
        __syncthreads();
    }
    if (t < NB) cur[t] = (sb[t] - v) + local[(size_t)t * nchunk + c];
    __syncthreads();
    int base = c * CHUNK;
    int end = min(base + CHUNK, E);
    for (int i = base + threadIdx.x; i < end; i += 512) {
        int d = dst[i], s = src[i];
        int b = d >> BK_SHIFT;
        int pos = atomicAdd(&cur[b], 1);
        ebuf[pos] = (uint)s | ((uint)(d & (BK_SIZE - 1)) << 24);
    }
}

// One block (1024 threads) per bucket of 256 nodes: LDS count/scan/sort.
// Pads each node's edge list to a multiple of 4 with sentinel src = N.
// Fused xprep tail: block b writes xs rows for its 256 nodes.
// Bucket range [e0,e1) from in-block 512-wide LDS scan of tot (NB <= 512).
__global__ __launch_bounds__(1024) void bucket_build_kernel(
        const uint* __restrict__ ebuf, const int* __restrict__ tot,
        int* __restrict__ deg_e, int* __restrict__ offsets,
        float* __restrict__ dis, int* __restrict__ ssrc,
        const float* __restrict__ x, uint* __restrict__ xs, int N, int NB) {
    __shared__ int sb[512];
    __shared__ int cnt[256], off[256], cur[256];
    __shared__ float sdis[256];
    int b = blockIdx.x;
    int t = threadIdx.x;
    if (t < 512) sb[t] = (t < NB) ? tot[t] : 0;
    if (t < 256) cnt[t] = 0;
    __syncthreads();
    for (int o = 1; o < 512; o <<= 1) {
        int u = (t >= o && t < 512) ? sb[t - o] : 0;
        __syncthreads();
        if (t < 512) sb[t] += u;
        __syncthreads();
    }
    int e1 = sb[b];                 // inclusive scan at b
    int e0 = e1 - tot[b];
    for (int i = e0 + t; i < e1; i += 1024)
        atomicAdd(&cnt[ebuf[i] >> 24], 1);
    __syncthreads();
    int v = (t < 256) ? cnt[t] : 0;
    int vpad = (v + 3) & ~3;
    if (t < 256) off[t] = vpad;
    __syncthreads();
    for (int o = 1; o < 256; o <<= 1) {
        int u = (t >= o && t < 256) ? off[t - o] : 0;
        __syncthreads();
        if (t < 256) off[t] += u;
        __syncthreads();
    }
    int base_pad = b * (CAP + 768);
    if (t < 256) {
        int excl = off[t] - vpad;
        int d = b * BK_SIZE + t;
        float dv = rsqrtf((float)(v + 1));
        sdis[t] = dv;
        if (d < N) {
            deg_e[d] = vpad;
            offsets[d] = base_pad + excl;
            dis[d] = dv;
        }
        cur[t] = excl;
    }
    __syncthreads();
    for (int i = e0 + t; i < e1; i += 1024) {
        uint e = ebuf[i];
        int ld = e >> 24;
        int pos = atomicAdd(&cur[ld], 1);
        ssrc[base_pad + pos] = (int)(e & 0xFFFFFFu);
    }
    __syncthreads();
    if (t < 256) {
        int excl = off[t] - vpad;
        for (int i = v; i < vpad; i++)
            ssrc[base_pad + excl + i] = N;
    }
    // fused xprep: 256 nodes x 32 uint2 (4 floats each) = 8192 items
    for (int i = t; i < 256 * 32; i += 1024) {
        int nl = i >> 5;                // node within bucket
        int w = i & 31;                 // uint2 within row
        int d = b * BK_SIZE + nl;
        if (d > N) continue;
        size_t oi = (size_t)d * 32 + w;
        if (d == N) { ((uint2*)xs)[oi] = make_uint2(0u, 0u); continue; }
        float dn = sdis[nl];
        float4 vv = ((const float4*)x)[oi];
        uint2 o;
        o.x = (uint)f2bf(dn * vv.x) | ((uint)f2bf(dn * vv.y) << 16);
        o.y = (uint)f2bf(dn * vv.z) | ((uint)f2bf(dn * vv.w) << 16);
        ((uint2*)xs)[oi] = o;
    }
}

// --- compute pipeline --------------------------------------------------------

// zb[d] = bf16(dis[d]*(sum_e xs[s] + xs[d])).  2 nodes/wave (32-lane halves;
// 4 groups x 8 lanes; 4-edge rounds match pad-4).  Feature half selected by
// bit 2 of blockIdx&7 (XCD round-robin).  oct0 = base node-octet.
__global__ void aggx_kernel(const uint* __restrict__ xs, const int* __restrict__ ssrc,
                            const int* __restrict__ offsets, const int* __restrict__ deg_e,
                            const float* __restrict__ dis, uint* __restrict__ zb,
                            int oct0, int N) {
    int lane = threadIdx.x & 63;
    int half = lane >> 5;
    int hl = lane & 31;
    int grp = hl >> 3;
    int ck = hl & 7;
    int j = blockIdx.x & 7;                        // XCD (empirical mapping)
    int fo = (j >> 2) << 5;                        // feature-half offset in uints
    int oct = oct0 + ((blockIdx.x >> 3) << 2) + (j & 3);  // node octet index
    int n = (oct << 3) + ((threadIdx.x >> 6) << 1) + half;
    if (n >= N) return;
    float acc[8];
#pragma unroll
    for (int i = 0; i < 8; i++) acc[i] = 0.f;
    int start = offsets[n], cnt = deg_e[n];  // cnt % 4 == 0
    uint4 uself = *(const uint4*)(xs + ((size_t)n << 6) + fo + (ck << 2));  // prefetch self
    int hbase = half << 5;
    for (int base = 0; base < cnt; base += 32) {
        int m = min(32, cnt - base);
        int idx = base + hl;
        int sv = ssrc[start + (idx < cnt ? idx : cnt - 1)];
        int rounds = m >> 2;  // 1..8
        int q = 0;
        for (; q + 4 <= rounds; q += 4) {
            int sA = __shfl(sv, hbase | ((q + 0) << 2) | grp);
            int sB = __shfl(sv, hbase | ((q + 1) << 2) | grp);
            int sC = __shfl(sv, hbase | ((q + 2) << 2) | grp);
            int sD = __shfl(sv, hbase | ((q + 3) << 2) | grp);
            uint4 uA = *(const uint4*)(xs + ((size_t)sA << 6) + fo + (ck << 2));
            uint4 uB = *(const uint4*)(xs + ((size_t)sB << 6) + fo + (ck << 2));
            uint4 uC = *(const uint4*)(xs + ((size_t)sC << 6) + fo + (ck << 2));
            uint4 uD = *(const uint4*)(xs + ((size_t)sD << 6) + fo + (ck << 2));
            ACC8(uA); ACC8(uB); ACC8(uC); ACC8(uD);
        }
        for (; q < rounds; q++) {
            int s = __shfl(sv, hbase | (q << 2) | grp);
            uint4 u = *(const uint4*)(xs + ((size_t)s << 6) + fo + (ck << 2));
            ACC8(u);
        }
    }
#pragma unroll
    for (int i = 0; i < 8; i++) acc[i] += __shfl_down(acc[i], 16);
#pragma unroll
    for (int i = 0; i < 8; i++) acc[i] += __shfl_down(acc[i], 8);
    if (grp == 0) {
        ACC8(uself);  // self-loop term
        float dn = dis[n];
        uint4 o;
        o.x = (uint)f2bf(dn * acc[0]) | ((uint)f2bf(dn * acc[1]) << 16);
        o.y = (uint)f2bf(dn * acc[2]) | ((uint)f2bf(dn * acc[3]) << 16);
        o.z = (uint)f2bf(dn * acc[4]) | ((uint)f2bf(dn * acc[5]) << 16);
        o.w = (uint)f2bf(dn * acc[6]) | ((uint)f2bf(dn * acc[7]) << 16);
        *(uint4*)(zb + ((size_t)n << 6) + fo + (ck << 2)) = o;
    }
}

// out1b = bf16(zb @ W1 + b1) + per-block BN partials.
__global__ __launch_bounds__(256) void gemm1_kernel(const uint* __restrict__ zb,
                                                    const uint* __restrict__ W1bp,
                                                    const float* __restrict__ b1,
                                                    ushort* __restrict__ out1b,
                                                    float* __restrict__ bnp, int N) {
    __shared__ uint sbuf[8192];  // A tile (16 KB) then C staging (32 KB)
    int t = threadIdx.x;
    int n0 = blockIdx.x * 64;
    for (int i = t; i < 64 * 16; i += 256) {
        int r = i >> 4, q = i & 15;
        int node = n0 + r;
        uint4 v = make_uint4(0u, 0u, 0u, 0u);
        if (node < N) v = *(const uint4*)(zb + (size_t)node * 64 + q * 4);
        int p = q ^ (r & 15);  // XOR swizzle: conflict-free b128
        *(uint4*)(&sbuf[r * 64 + p * 4]) = v;
    }
    __syncthreads();
    int wave = t >> 6, lane = t & 63;
    int quad = lane >> 4, lrow = lane & 15;
    f32x4 acc[4][4];
#pragma unroll
    for (int m = 0; m < 4; m++)
#pragma unroll
        for (int nt = 0; nt < 4; nt++) acc[m][nt] = (f32x4)(0.f);
#pragma unroll
    for (int kc = 0; kc < 4; kc++) {
        bf16x8 bfr[4];
#pragma unroll
        for (int nt = 0; nt < 4; nt++) {
            int c = wave * 64 + nt * 16 + lrow;
            bfr[nt] = *(const bf16x8*)(W1bp + ((size_t)(kc * 256 + c) * 16 + quad * 4));
        }
        bf16x8 afr[4];
#pragma unroll
        for (int m = 0; m < 4; m++) {
            int p = (kc * 4 + quad) ^ lrow;
            afr[m] = *(const bf16x8*)(&sbuf[(m * 16 + lrow) * 64 + p * 4]);
        }
#pragma unroll
        for (int m = 0; m < 4; m++)
#pragma unroll
            for (int nt = 0; nt < 4; nt++)
                acc[m][nt] = __builtin_amdgcn_mfma_f32_16x16x32_bf16(
                    afr[m], bfr[nt], acc[m][nt], 0, 0, 0);
    }
    __syncthreads();  // A reads done; reuse sbuf for C staging
#pragma unroll
    for (int nt = 0; nt < 4; nt++) {
        int c = wave * 64 + nt * 16 + lrow;
        float bb = b1[c];
        float s = 0.f, q = 0.f;
#pragma unroll
        for (int m = 0; m < 4; m++) {
#pragma unroll
            for (int r = 0; r < 4; r++) {
                int row = m * 16 + quad * 4 + r;
                float v = acc[m][nt][r] + bb;
                if (n0 + row < N) { s += v; q = fmaf(v, v, q); }
                uint hv = (uint)f2bf(v);
                uint pv = __shfl_xor(hv, 1);
                if ((lrow & 1) == 0)
                    sbuf[row * 128 + (c >> 1)] = hv | (pv << 16);
            }
        }
        s += __shfl_down(s, 32); q += __shfl_down(q, 32);
        s += __shfl_down(s, 16); q += __shfl_down(q, 16);
        if (quad == 0) {
            bnp[(size_t)blockIdx.x * 512 + c] = s;
            bnp[(size_t)blockIdx.x * 512 + 256 + c] = q;
        }
    }
    __syncthreads();
    uint* out1g = (uint*)out1b;
    for (int i = t; i < 2048; i += 256) {  // 64 rows x 32 uint4
        int row = i >> 5;
        if (n0 + row < N)
            *(uint4*)(out1g + (size_t)(n0 + row) * 128 + (i & 31) * 4) =
                *(const uint4*)(&sbuf[i * 4]);
    }
}

// Single-stage BN partial reduce: 32 blocks, atomic-add final sums (zeroed).
__global__ void bnred_kernel(const float* __restrict__ bnp, float* __restrict__ bnsum,
                             int nblk) {
    int g = blockIdx.x, t = threadIdx.x;
    float s = 0.f, q = 0.f;
    for (int b = g; b < nblk; b += 32) {
        s += bnp[(size_t)b * 512 + t];
        q += bnp[(size_t)b * 512 + 256 + t];
    }
    atomicAdd(&bnsum[t], s);
    atomicAdd(&bnsum[256 + t], q);
}

// gs = bf16(dis * (relu(bn(out1b)) @ W2)); scale/bias computed in prologue.
__global__ __launch_bounds__(256) void gemm2_kernel(const ushort* __restrict__ out1b,
                                                    const uint* __restrict__ W2bp,
                                                    const float* __restrict__ dis,
                                                    const float* __restrict__ bnsum,
                                                    const float* __restrict__ gamma,
                                                    const float* __restrict__ beta,
                                                    ushort* __restrict__ gs, int N) {
    __shared__ uint sbuf[8192];
    __shared__ float bns[256], bnb[256];
    const uint* out1u = (const uint*)out1b;
    int t = threadIdx.x;
    int n0 = blockIdx.x * 64;
    if (blockIdx.x == 0 && t < 32) ((uint*)gs)[(size_t)N * 32 + t] = 0u;  // sentinel row
    {
        float invN = 1.0f / (float)N;
        float mean = bnsum[t] * invN;
        float var = bnsum[256 + t] * invN - mean * mean;
        float sc = gamma[t] * rsqrtf(fmaxf(var, 0.f) + 1e-5f);
        bns[t] = sc;
        bnb[t] = beta[t] - mean * sc;
    }
    __syncthreads();
    for (int i = t; i < 64 * 32; i += 256) {
        int r = i >> 5, q = i & 31;
        int node = n0 + r;
        uint4 v = make_uint4(0u, 0u, 0u, 0u);
        if (node < N) {
            uint4 w = *(const uint4*)(out1u + (size_t)node * 128 + q * 4);
            int c0 = q * 8;
            float r0 = fmaxf(fmaf(bf_lo(w.x), bns[c0 + 0], bnb[c0 + 0]), 0.f);
            float r1 = fmaxf(fmaf(bf_hi(w.x), bns[c0 + 1], bnb[c0 + 1]), 0.f);
            float r2 = fmaxf(fmaf(bf_lo(w.y), bns[c0 + 2], bnb[c0 + 2]), 0.f);
            float r3 = fmaxf(fmaf(bf_hi(w.y), bns[c0 + 3], bnb[c0 + 3]), 0.f);
            float r4 = fmaxf(fmaf(bf_lo(w.z), bns[c0 + 4], bnb[c0 + 4]), 0.f);
            float r5 = fmaxf(fmaf(bf_hi(w.z), bns[c0 + 5], bnb[c0 + 5]), 0.f);
            float r6 = fmaxf(fmaf(bf_lo(w.w), bns[c0 + 6], bnb[c0 + 6]), 0.f);
            float r7 = fmaxf(fmaf(bf_hi(w.w), bns[c0 + 7], bnb[c0 + 7]), 0.f);
            v.x = (uint)f2bf(r0) | ((uint)f2bf(r1) << 16);
            v.y = (uint)f2bf(r2) | ((uint)f2bf(r3) << 16);
            v.z = (uint)f2bf(r4) | ((uint)f2bf(r5) << 16);
            v.w = (uint)f2bf(r6) | ((uint)f2bf(r7) << 16);
        }
        int p = (q & 16) | ((q & 15) ^ (r & 15));  // XOR swizzle (low 4 bits)
        *(uint4*)(&sbuf[r * 128 + p * 4]) = v;
    }
    __syncthreads();
    int wave = t >> 6, lane = t & 63;
    int quad = lane >> 4, lrow = lane & 15;
    int c = wave * 16 + lrow;
    f32x4 acc[4];
#pragma unroll
    for (int m = 0; m < 4; m++) acc[m] = (f32x4)(0.f);
#pragma unroll
    for (int kc = 0; kc < 8; kc++) {
        bf16x8 bfr = *(const bf16x8*)(W2bp + ((size_t)(kc * 64 + c) * 16 + quad * 4));
#pragma unroll
        for (int m = 0; m < 4; m++) {
            int q = kc * 4 + quad;
            int p = (q & 16) | ((q & 15) ^ lrow);
            bf16x8 afr = *(const bf16x8*)(&sbuf[(m * 16 + lrow) * 128 + p * 4]);
            acc[m] = __builtin_amdgcn_mfma_f32_16x16x32_bf16(afr, bfr, acc[m], 0, 0, 0);
        }
    }
    __syncthreads();
#pragma unroll
    for (int m = 0; m < 4; m++) {
#pragma unroll
        for (int r = 0; r < 4; r++) {
            int row = m * 16 + quad * 4 + r;
            int node = n0 + row;
            float dn = (node < N) ? dis[node] : 0.f;
            uint hv = (uint)f2bf(dn * acc[m][r]);
            uint pv = __shfl_xor(hv, 1);
            if ((lrow & 1) == 0)
                sbuf[row * 32 + (c >> 1)] = hv | (pv << 16);
        }
    }
    __syncthreads();
    uint* gsg = (uint*)gs;
    for (int i = t; i < 512; i += 256) {
        int row = i >> 3;
        if (n0 + row < N)
            *(uint4*)(gsg + (size_t)(n0 + row) * 32 + (i & 7) * 4) =
                *(const uint4*)(&sbuf[i * 4]);
    }
}

// out[d] = dis[d]*(sum_e gs[s] + gs[d]) + b2.  2 nodes per wave (32-lane
// halves); 4 groups x 8 lanes per half; 4 edges/round (matches pad-4).
// 4-deep batched gathers + self-row prefetch.
__global__ void agg2_kernel(const uint* __restrict__ gs, const int* __restrict__ ssrc,
                            const int* __restrict__ offsets, const int* __restrict__ deg_e,
                            const float* __restrict__ dis, const float* __restrict__ b2,
                            float* __restrict__ out, int N) {
    int lane = threadIdx.x & 63;
    int half = lane >> 5;
    int hl = lane & 31;
    int grp = hl >> 3;
    int ck = hl & 7;
    int n = blockIdx.x * 8 + ((threadIdx.x >> 6) << 1) + half;
    if (n >= N) return;
    float acc[8];
#pragma unroll
    for (int i = 0; i < 8; i++) acc[i] = 0.f;
    int start = offsets[n], cnt = deg_e[n];  // cnt % 4 == 0
    uint4 uself = *(const uint4*)(gs + ((size_t)n << 5) + (ck << 2));  // prefetch self
    int hbase = half << 5;
    for (int base = 0; base < cnt; base += 32) {
        int m = min(32, cnt - base);
        int idx = base + hl;
        int sv = ssrc[start + (idx < cnt ? idx : cnt - 1)];
        int rounds = m >> 2;  // 1..8
        int q = 0;
        for (; q + 4 <= rounds; q += 4) {
            int sA = __shfl(sv, hbase | ((q + 0) << 2) | grp);
            int sB = __shfl(sv, hbase | ((q + 1) << 2) | grp);
            int sC = __shfl(sv, hbase | ((q + 2) << 2) | grp);
            int sD = __shfl(sv, hbase | ((q + 3) << 2) | grp);
            uint4 uA = *(const uint4*)(gs + ((size_t)sA << 5) + (ck << 2));
            uint4 uB = *(const uint4*)(gs + ((size_t)sB << 5) + (ck << 2));
            uint4 uC = *(const uint4*)(gs + ((size_t)sC << 5) + (ck << 2));
            uint4 uD = *(const uint4*)(gs + ((size_t)sD << 5) + (ck << 2));
            ACC8(uA); ACC8(uB); ACC8(uC); ACC8(uD);
        }
        for (; q + 2 <= rounds; q += 2) {
            int sA = __shfl(sv, hbase | ((q + 0) << 2) | grp);
            int sB = __shfl(sv, hbase | ((q + 1) << 2) | grp);
            uint4 uA = *(const uint4*)(gs + ((size_t)sA << 5) + (ck << 2));
            uint4 uB = *(const uint4*)(gs + ((size_t)sB << 5) + (ck << 2));
            ACC8(uA); ACC8(uB);
        }
        for (; q < rounds; q++) {
            int s = __shfl(sv, hbase | (q << 2) | grp);
            uint4 u = *(const uint4*)(gs + ((size_t)s << 5) + (ck << 2));
            ACC8(u);
        }
    }
#pragma unroll
    for (int i = 0; i < 8; i++) acc[i] += __shfl_down(acc[i], 16);
#pragma unroll
    for (int i = 0; i < 8; i++) acc[i] += __shfl_down(acc[i], 8);
    if (grp == 0) {
        ACC8(uself);  // self-loop term
        float dn = dis[n];
        float4 bb0 = *(const float4*)(b2 + ck * 8);
        float4 bb1 = *(const float4*)(b2 + ck * 8 + 4);
        float* op = out + (size_t)n * OUT_F + ck * 8;
        *(float4*)op = make_float4(fmaf(dn, acc[0], bb0.x), fmaf(dn, acc[1], bb0.y),
                                   fmaf(dn, acc[2], bb0.z), fmaf(dn, acc[3], bb0.w));
        *(float4*)(op + 4) = make_float4(fmaf(dn, acc[4], bb1.x), fmaf(dn, acc[5], bb1.y),
                                         fmaf(dn, acc[6], bb1.z), fmaf(dn, acc[7], bb1.w));
    }
}

extern "C" void kernel_launch(void* const* d_in, const int* in_sizes, int n_in,
                              void* d_out, int out_size, void* d_ws, size_t ws_size,
                              hipStream_t stream) {
    const float* x      = (const float*)d_in[0];
    const int*   edges  = (const int*)d_in[1];
    const float* W1     = (const float*)d_in[2];
    const float* b1     = (const float*)d_in[3];
    const float* gamma1 = (const float*)d_in[4];
    const float* beta1  = (const float*)d_in[5];
    const float* W2     = (const float*)d_in[6];
    const float* b2     = (const float*)d_in[7];
    float* out = (float*)d_out;

    int N = in_sizes[0] / IN_F;
    int E = in_sizes[1] / 2;
    const int* src = edges;
    const int* dst = edges + E;
    int NB = (N + BK_SIZE - 1) / BK_SIZE;   // 391 (<= 512 required)
    int nchunks = (E + CHUNK - 1) / CHUNK;  // 196 (<= 256 required)
    int M = NB * nchunks;
    int nblk1 = (N + 63) / 64;

    char* ws = (char*)d_ws;
    size_t off = 0;
    auto alloc = [&](size_t bytes) -> void* {
        void* p = ws + off;
        off += (bytes + 255) & ~(size_t)255;
        return p;
    };
    int*    deg_e   = (int*)alloc((size_t)N * 4);
    int*    offsets = (int*)alloc((size_t)N * 4);
    float*  dis     = (float*)alloc((size_t)(N + 1) * 4);
    float*  bnsum   = (float*)alloc(512 * 4);   // sums | sumsq (zeroed)
    int*    cnts    = (int*)alloc((size_t)M * 4);
    int*    local   = (int*)alloc((size_t)M * 4);
    int*    tot     = (int*)alloc(512 * 4);
    int*    ssrc    = (int*)alloc((size_t)NB * (CAP + 768) * 4);  // padded CSR
    uint*   ebuf    = (uint*)alloc((size_t)E * 4);                // packed
    uint*   xs      = (uint*)alloc((size_t)(N + 1) * (IN_F / 2) * 4); // +sentinel row
    uint*   zb      = (uint*)alloc((size_t)N * (IN_F / 2) * 4);
    ushort* out1b   = (ushort*)alloc((size_t)N * HID_F * 2);
    float*  bnp     = (float*)alloc((size_t)nblk1 * 512 * 4);         // block partials
    ushort* W1bp    = (ushort*)alloc(4 * 256 * 32 * 2);
    ushort* W2bp    = (ushort*)alloc(8 * 64 * 32 * 2);
    ushort* gs      = (ushort*)zb;  // alias: zb dead after gemm1; (N+1) rows x 64 bf16

    hipMemsetAsync(bnsum, 0, 512 * 4, stream);

    count_wprep_kernel<<<nchunks + 96, 512, 0, stream>>>(dst, cnts, W1, W2, W1bp, W2bp,
                                                         E, NB, nchunks);
    scan_bucket_kernel<<<NB, 256, 0, stream>>>(cnts, local, tot, nchunks);
    scatter_kernel<<<nchunks, 512, 0, stream>>>(src, dst, local, tot, ebuf, E, NB, nchunks);
    bucket_build_kernel<<<NB, 1024, 0, stream>>>(ebuf, tot, deg_e, offsets, dis, ssrc,
                                                 x, xs, N, NB);
    {
        int noct = (N + 7) >> 3;                  // 12500 node octets
        int h0 = ((noct / 2 + 3) >> 2) << 2;      // 6252 (multiple of 4)
        int h1 = noct - h0;                       // 6248
        int grid0 = (h0 >> 2) << 3;               // 2 feature halves x 4 octets / 8 blocks
        int grid1 = ((h1 + 3) >> 2) << 3;
        aggx_kernel<<<grid0, 256, 0, stream>>>(xs, ssrc, offsets, deg_e, dis, zb, 0, N);
        aggx_kernel<<<grid1, 256, 0, stream>>>(xs, ssrc, offsets, deg_e, dis, zb, h0, N);
    }
    gemm1_kernel<<<nblk1, 256, 0, stream>>>(zb, (const uint*)W1bp, b1, out1b, bnp, N);
    bnred_kernel<<<32, 256, 0, stream>>>(bnp, bnsum, nblk1);
    gemm2_kernel<<<nblk1, 256, 0, stream>>>(out1b, (const uint*)W2bp, dis, bnsum,
                                            gamma1, beta1, gs, N);
    agg2_kernel<<<(N + 7) / 8, 256, 0, stream>>>((const uint*)gs, ssrc, offsets, deg_e, dis,
                                                 b2, out, N);
}

// Round 13
// 321.244 us; speedup vs baseline: 1.3674x; 1.0196x over previous
//
#include <hip/hip_runtime.h>
#include <hip/hip_bf16.h>

// GraphSAINT 2-layer GCN forward on MI355X.
// Layer 1: xs[n] = bf16(dis[n]*x[n]);  zb[d] = bf16(dis[d]*(sum_e xs[s] + xs[d]));
//          out1b = bf16(zb @ W1 + b1)   (bf16 MFMA; BN partials fused).
// Layer 2: gs[n] = bf16(dis[n]*(relu(bn(out1b[n])) @ W2))  (bf16 MFMA);
//          out[d] = dis[d]*(sum_e gs[s] + gs[d]) + b2  (fp32).
// R28: (a) sort reverted to the R24 fused atomic form -- R27 proved the
// atomic-free split costs +15 us net (extra dst pass + launches) despite the
// cleaner structure.  (b) gemm1 epilogue rebuilt: C-staging LDS deleted;
// paired-bf16 values stored DIRECTLY to out1b (each quad's 8 even lanes write
// one 32B segment; L2 writeback merges adjacent nt-iterations into full
// lines).  LDS 32->16 KB (residency cap 5->10 blocks/CU), two syncthreads and
// the whole LDS round-trip removed -- R27 profile showed gemm1 =40.9 us
// latency-bound at 19% occupancy with nothing saturated.  aggx keeps the
// two-dispatch split (visibility, neutral).  All other kernels byte-identical
// to the measured R24 build (312.4 us).

#define IN_F  128
#define HID_F 256
#define OUT_F 64
#define BK_SHIFT 8
#define BK_SIZE  256
#define CHUNK    8192
#define CAP      8192   // per-bucket edge capacity (mean 4092, sigma ~64)

typedef unsigned int uint;
typedef unsigned short ushort;
typedef short bf16x8 __attribute__((ext_vector_type(8)));
typedef float f32x4 __attribute__((ext_vector_type(4)));

__device__ __forceinline__ ushort f2bf(float f) {
    uint u = __float_as_uint(f);
    uint r = (u + 0x7fffu + ((u >> 16) & 1u)) >> 16;  // RNE
    return (ushort)r;
}
__device__ __forceinline__ float bf_lo(uint u) { return __uint_as_float(u << 16); }
__device__ __forceinline__ float bf_hi(uint u) { return __uint_as_float(u & 0xffff0000u); }

#define ACC8(u)                                         \
    do {                                                \
        acc[0] += bf_lo((u).x); acc[1] += bf_hi((u).x); \
        acc[2] += bf_lo((u).y); acc[3] += bf_hi((u).y); \
        acc[4] += bf_lo((u).z); acc[5] += bf_hi((u).z); \
        acc[6] += bf_lo((u).w); acc[7] += bf_hi((u).w); \
    } while (0)

// --- sort pipeline -----------------------------------------------------------

// Blocks [0,nchunk): bucket edges into fixed-capacity regions (512 threads).
// Blocks [nchunk, nchunk+96): W1/W2 repack into MFMA B-fragment layout.
__global__ __launch_bounds__(512) void scatter_wprep_kernel(
        const int* __restrict__ src, const int* __restrict__ dst,
        int* __restrict__ bcursor, uint* __restrict__ ebuf,
        const float* __restrict__ W1, const float* __restrict__ W2,
        ushort* __restrict__ W1bp, ushort* __restrict__ W2bp,
        int E, int NB, int nchunk) {
    if (blockIdx.x >= nchunk) {
        int i = (blockIdx.x - nchunk) * 512 + threadIdx.x;  // 49152 total
        if (i < 32768) {
            int kk = i & 31, c = (i >> 5) & 255, kc = i >> 13;
            W1bp[i] = f2bf(W1[(size_t)(kc * 32 + kk) * HID_F + c]);
        } else {
            int j = i - 32768;
            int kk = j & 31, c = (j >> 5) & 63, kc = j >> 11;
            W2bp[j] = f2bf(W2[(size_t)(kc * 32 + kk) * OUT_F + c]);
        }
        return;
    }
    __shared__ int h[512];
    __shared__ int cur[512];
    for (int i = threadIdx.x; i < NB; i += 512) h[i] = 0;
    __syncthreads();
    int base = blockIdx.x * CHUNK;
    int end = min(base + CHUNK, E);
    for (int i = base + threadIdx.x; i < end; i += 512)
        atomicAdd(&h[dst[i] >> BK_SHIFT], 1);
    __syncthreads();
    for (int i = threadIdx.x; i < NB; i += 512)
        cur[i] = i * CAP + (h[i] ? atomicAdd(&bcursor[i], h[i]) : 0);
    __syncthreads();
    for (int i = base + threadIdx.x; i < end; i += 512) {
        int d = dst[i], s = src[i];
        int b = d >> BK_SHIFT;
        int pos = atomicAdd(&cur[b], 1);
        ebuf[pos] = (uint)s | ((uint)(d & (BK_SIZE - 1)) << 24);
    }
}

// One block (1024 threads) per bucket of 256 nodes: LDS count/scan/sort.
// Pads each node's edge list to a multiple of 4 with sentinel src = N.
// Fused xprep tail: block b writes xs rows for its 256 nodes
// (xs[n] = bf16(dis[n]*x[n]); row N zeros), dis taken from LDS.
__global__ __launch_bounds__(1024) void bucket_build_kernel(
        const uint* __restrict__ ebuf, const int* __restrict__ bcursor,
        int* __restrict__ deg_e, int* __restrict__ offsets,
        float* __restrict__ dis, int* __restrict__ ssrc,
        const float* __restrict__ x, uint* __restrict__ xs, int N) {
    __shared__ int cnt[256], off[256], cur[256];
    __shared__ float sdis[256];
    int b = blockIdx.x;
    int t = threadIdx.x;
    if (t < 256) cnt[t] = 0;
    __syncthreads();
    int e0 = b * CAP;
    int e1 = e0 + min(bcursor[b], CAP);
    for (int i = e0 + t; i < e1; i += 1024)
        atomicAdd(&cnt[ebuf[i] >> 24], 1);
    __syncthreads();
    int v = (t < 256) ? cnt[t] : 0;
    int vpad = (v + 3) & ~3;
    if (t < 256) off[t] = vpad;
    __syncthreads();
    for (int o = 1; o < 256; o <<= 1) {
        int u = (t >= o && t < 256) ? off[t - o] : 0;
        __syncthreads();
        if (t < 256) off[t] += u;
        __syncthreads();
    }
    int base_pad = b * (CAP + 768);
    if (t < 256) {
        int excl = off[t] - vpad;
        int d = b * BK_SIZE + t;
        float dv = rsqrtf((float)(v + 1));
        sdis[t] = dv;
        if (d < N) {
            deg_e[d] = vpad;
            offsets[d] = base_pad + excl;
            dis[d] = dv;
        }
        cur[t] = excl;
    }
    __syncthreads();
    for (int i = e0 + t; i < e1; i += 1024) {
        uint e = ebuf[i];
        int ld = e >> 24;
        int pos = atomicAdd(&cur[ld], 1);
        ssrc[base_pad + pos] = (int)(e & 0xFFFFFFu);
    }
    __syncthreads();
    if (t < 256) {
        int excl = off[t] - vpad;
        for (int i = v; i < vpad; i++)
            ssrc[base_pad + excl + i] = N;
    }
    // fused xprep: 256 nodes x 32 uint2 (4 floats each) = 8192 items
    for (int i = t; i < 256 * 32; i += 1024) {
        int nl = i >> 5;                // node within bucket
        int w = i & 31;                 // uint2 within row
        int d = b * BK_SIZE + nl;
        if (d > N) continue;
        size_t oi = (size_t)d * 32 + w;
        if (d == N) { ((uint2*)xs)[oi] = make_uint2(0u, 0u); continue; }
        float dn = sdis[nl];
        float4 vv = ((const float4*)x)[oi];
        uint2 o;
        o.x = (uint)f2bf(dn * vv.x) | ((uint)f2bf(dn * vv.y) << 16);
        o.y = (uint)f2bf(dn * vv.z) | ((uint)f2bf(dn * vv.w) << 16);
        ((uint2*)xs)[oi] = o;
    }
}

// --- compute pipeline --------------------------------------------------------

// zb[d] = bf16(dis[d]*(sum_e xs[s] + xs[d])).  2 nodes/wave (32-lane halves;
// 4 groups x 8 lanes; 4-edge rounds match pad-4).  Feature half selected by
// bit 2 of blockIdx&7 (XCD round-robin).  oct0 = base node-octet.
__global__ void aggx_kernel(const uint* __restrict__ xs, const int* __restrict__ ssrc,
                            const int* __restrict__ offsets, const int* __restrict__ deg_e,
                            const float* __restrict__ dis, uint* __restrict__ zb,
                            int oct0, int N) {
    int lane = threadIdx.x & 63;
    int half = lane >> 5;
    int hl = lane & 31;
    int grp = hl >> 3;
    int ck = hl & 7;
    int j = blockIdx.x & 7;                        // XCD (empirical mapping)
    int fo = (j >> 2) << 5;                        // feature-half offset in uints
    int oct = oct0 + ((blockIdx.x >> 3) << 2) + (j & 3);  // node octet index
    int n = (oct << 3) + ((threadIdx.x >> 6) << 1) + half;
    if (n >= N) return;
    float acc[8];
#pragma unroll
    for (int i = 0; i < 8; i++) acc[i] = 0.f;
    int start = offsets[n], cnt = deg_e[n];  // cnt % 4 == 0
    uint4 uself = *(const uint4*)(xs + ((size_t)n << 6) + fo + (ck << 2));  // prefetch self
    int hbase = half << 5;
    for (int base = 0; base < cnt; base += 32) {
        int m = min(32, cnt - base);
        int idx = base + hl;
        int sv = ssrc[start + (idx < cnt ? idx : cnt - 1)];
        int rounds = m >> 2;  // 1..8
        int q = 0;
        for (; q + 4 <= rounds; q += 4) {
            int sA = __shfl(sv, hbase | ((q + 0) << 2) | grp);
            int sB = __shfl(sv, hbase | ((q + 1) << 2) | grp);
            int sC = __shfl(sv, hbase | ((q + 2) << 2) | grp);
            int sD = __shfl(sv, hbase | ((q + 3) << 2) | grp);
            uint4 uA = *(const uint4*)(xs + ((size_t)sA << 6) + fo + (ck << 2));
            uint4 uB = *(const uint4*)(xs + ((size_t)sB << 6) + fo + (ck << 2));
            uint4 uC = *(const uint4*)(xs + ((size_t)sC << 6) + fo + (ck << 2));
            uint4 uD = *(const uint4*)(xs + ((size_t)sD << 6) + fo + (ck << 2));
            ACC8(uA); ACC8(uB); ACC8(uC); ACC8(uD);
        }
        for (; q < rounds; q++) {
            int s = __shfl(sv, hbase | (q << 2) | grp);
            uint4 u = *(const uint4*)(xs + ((size_t)s << 6) + fo + (ck << 2));
            ACC8(u);
        }
    }
#pragma unroll
    for (int i = 0; i < 8; i++) acc[i] += __shfl_down(acc[i], 16);
#pragma unroll
    for (int i = 0; i < 8; i++) acc[i] += __shfl_down(acc[i], 8);
    if (grp == 0) {
        ACC8(uself);  // self-loop term
        float dn = dis[n];
        uint4 o;
        o.x = (uint)f2bf(dn * acc[0]) | ((uint)f2bf(dn * acc[1]) << 16);
        o.y = (uint)f2bf(dn * acc[2]) | ((uint)f2bf(dn * acc[3]) << 16);
        o.z = (uint)f2bf(dn * acc[4]) | ((uint)f2bf(dn * acc[5]) << 16);
        o.w = (uint)f2bf(dn * acc[6]) | ((uint)f2bf(dn * acc[7]) << 16);
        *(uint4*)(zb + ((size_t)n << 6) + fo + (ck << 2)) = o;
    }
}

// out1b = bf16(zb @ W1 + b1) + per-block BN partials.
// R28: no C staging -- paired bf16 stored directly (quad's 8 even lanes =
// one 32B segment; L2 writeback merges).  LDS 16 KB, 2 fewer barriers.
__global__ __launch_bounds__(256) void gemm1_kernel(const uint* __restrict__ zb,
                                                    const uint* __restrict__ W1bp,
                                                    const float* __restrict__ b1,
                                                    ushort* __restrict__ out1b,
                                                    float* __restrict__ bnp, int N) {
    __shared__ uint sbuf[4096];  // A tile only (16 KB)
    int t = threadIdx.x;
    int n0 = blockIdx.x * 64;
    for (int i = t; i < 64 * 16; i += 256) {
        int r = i >> 4, q = i & 15;
        int node = n0 + r;
        uint4 v = make_uint4(0u, 0u, 0u, 0u);
        if (node < N) v = *(const uint4*)(zb + (size_t)node * 64 + q * 4);
        int p = q ^ (r & 15);  // XOR swizzle: conflict-free b128
        *(uint4*)(&sbuf[r * 64 + p * 4]) = v;
    }
    __syncthreads();
    int wave = t >> 6, lane = t & 63;
    int quad = lane >> 4, lrow = lane & 15;
    f32x4 acc[4][4];
#pragma unroll
    for (int m = 0; m < 4; m++)
#pragma unroll
        for (int nt = 0; nt < 4; nt++) acc[m][nt] = (f32x4)(0.f);
#pragma unroll
    for (int kc = 0; kc < 4; kc++) {
        bf16x8 bfr[4];
#pragma unroll
        for (int nt = 0; nt < 4; nt++) {
            int c = wave * 64 + nt * 16 + lrow;
            bfr[nt] = *(const bf16x8*)(W1bp + ((size_t)(kc * 256 + c) * 16 + quad * 4));
        }
        bf16x8 afr[4];
#pragma unroll
        for (int m = 0; m < 4; m++) {
            int p = (kc * 4 + quad) ^ lrow;
            afr[m] = *(const bf16x8*)(&sbuf[(m * 16 + lrow) * 64 + p * 4]);
        }
#pragma unroll
        for (int m = 0; m < 4; m++)
#pragma unroll
            for (int nt = 0; nt < 4; nt++)
                acc[m][nt] = __builtin_amdgcn_mfma_f32_16x16x32_bf16(
                    afr[m], bfr[nt], acc[m][nt], 0, 0, 0);
    }
    uint* out1g = (uint*)out1b;
#pragma unroll
    for (int nt = 0; nt < 4; nt++) {
        int c = wave * 64 + nt * 16 + lrow;
        float bb = b1[c];
        float s = 0.f, q = 0.f;
#pragma unroll
        for (int m = 0; m < 4; m++) {
#pragma unroll
            for (int r = 0; r < 4; r++) {
                int row = m * 16 + quad * 4 + r;
                float v = acc[m][nt][r] + bb;
                bool live = (n0 + row < N);
                if (live) { s += v; q = fmaf(v, v, q); }
                uint hv = (uint)f2bf(v);
                uint pv = __shfl_xor(hv, 1);
                if ((lrow & 1) == 0 && live)
                    out1g[(size_t)(n0 + row) * 128 + (c >> 1)] = hv | (pv << 16);
            }
        }
        s += __shfl_down(s, 32); q += __shfl_down(q, 32);
        s += __shfl_down(s, 16); q += __shfl_down(q, 16);
        if (quad == 0) {
            bnp[(size_t)blockIdx.x * 512 + c] = s;
            bnp[(size_t)blockIdx.x * 512 + 256 + c] = q;
        }
    }
}

// Single-stage BN partial reduce: 32 blocks, atomic-add final sums (zeroed).
__global__ void bnred_kernel(const float* __restrict__ bnp, float* __restrict__ bnsum,
                             int nblk) {
    int g = blockIdx.x, t = threadIdx.x;
    float s = 0.f, q = 0.f;
    for (int b = g; b < nblk; b += 32) {
        s += bnp[(size_t)b * 512 + t];
        q += bnp[(size_t)b * 512 + 256 + t];
    }
    atomicAdd(&bnsum[t], s);
    atomicAdd(&bnsum[256 + t], q);
}

// gs = bf16(dis * (relu(bn(out1b)) @ W2)); scale/bias computed in prologue.
__global__ __launch_bounds__(256) void gemm2_kernel(const ushort* __restrict__ out1b,
                                                    const uint* __restrict__ W2bp,
                                                    const float* __restrict__ dis,
                                                    const float* __restrict__ bnsum,
                                                    const float* __restrict__ gamma,
                                                    const float* __restrict__ beta,
                                                    ushort* __restrict__ gs, int N) {
    __shared__ uint sbuf[8192];
    __shared__ float bns[256], bnb[256];
    const uint* out1u = (const uint*)out1b;
    int t = threadIdx.x;
    int n0 = blockIdx.x * 64;
    if (blockIdx.x == 0 && t < 32) ((uint*)gs)[(size_t)N * 32 + t] = 0u;  // sentinel row
    {
        float invN = 1.0f / (float)N;
        float mean = bnsum[t] * invN;
        float var = bnsum[256 + t] * invN - mean * mean;
        float sc = gamma[t] * rsqrtf(fmaxf(var, 0.f) + 1e-5f);
        bns[t] = sc;
        bnb[t] = beta[t] - mean * sc;
    }
    __syncthreads();
    for (int i = t; i < 64 * 32; i += 256) {
        int r = i >> 5, q = i & 31;
        int node = n0 + r;
        uint4 v = make_uint4(0u, 0u, 0u, 0u);
        if (node < N) {
            uint4 w = *(const uint4*)(out1u + (size_t)node * 128 + q * 4);
            int c0 = q * 8;
            float r0 = fmaxf(fmaf(bf_lo(w.x), bns[c0 + 0], bnb[c0 + 0]), 0.f);
            float r1 = fmaxf(fmaf(bf_hi(w.x), bns[c0 + 1], bnb[c0 + 1]), 0.f);
            float r2 = fmaxf(fmaf(bf_lo(w.y), bns[c0 + 2], bnb[c0 + 2]), 0.f);
            float r3 = fmaxf(fmaf(bf_hi(w.y), bns[c0 + 3], bnb[c0 + 3]), 0.f);
            float r4 = fmaxf(fmaf(bf_lo(w.z), bns[c0 + 4], bnb[c0 + 4]), 0.f);
            float r5 = fmaxf(fmaf(bf_hi(w.z), bns[c0 + 5], bnb[c0 + 5]), 0.f);
            float r6 = fmaxf(fmaf(bf_lo(w.w), bns[c0 + 6], bnb[c0 + 6]), 0.f);
            float r7 = fmaxf(fmaf(bf_hi(w.w), bns[c0 + 7], bnb[c0 + 7]), 0.f);
            v.x = (uint)f2bf(r0) | ((uint)f2bf(r1) << 16);
            v.y = (uint)f2bf(r2) | ((uint)f2bf(r3) << 16);
            v.z = (uint)f2bf(r4) | ((uint)f2bf(r5) << 16);
            v.w = (uint)f2bf(r6) | ((uint)f2bf(r7) << 16);
        }
        int p = (q & 16) | ((q & 15) ^ (r & 15));  // XOR swizzle (low 4 bits)
        *(uint4*)(&sbuf[r * 128 + p * 4]) = v;
    }
    __syncthreads();
    int wave = t >> 6, lane = t & 63;
    int quad = lane >> 4, lrow = lane & 15;
    int c = wave * 16 + lrow;
    f32x4 acc[4];
#pragma unroll
    for (int m = 0; m < 4; m++) acc[m] = (f32x4)(0.f);
#pragma unroll
    for (int kc = 0; kc < 8; kc++) {
        bf16x8 bfr = *(const bf16x8*)(W2bp + ((size_t)(kc * 64 + c) * 16 + quad * 4));
#pragma unroll
        for (int m = 0; m < 4; m++) {
            int q = kc * 4 + quad;
            int p = (q & 16) | ((q & 15) ^ lrow);
            bf16x8 afr = *(const bf16x8*)(&sbuf[(m * 16 + lrow) * 128 + p * 4]);
            acc[m] = __builtin_amdgcn_mfma_f32_16x16x32_bf16(afr, bfr, acc[m], 0, 0, 0);
        }
    }
    __syncthreads();
#pragma unroll
    for (int m = 0; m < 4; m++) {
#pragma unroll
        for (int r = 0; r < 4; r++) {
            int row = m * 16 + quad * 4 + r;
            int node = n0 + row;
            float dn = (node < N) ? dis[node] : 0.f;
            uint hv = (uint)f2bf(dn * acc[m][r]);
            uint pv = __shfl_xor(hv, 1);
            if ((lrow & 1) == 0)
                sbuf[row * 32 + (c >> 1)] = hv | (pv << 16);
        }
    }
    __syncthreads();
    uint* gsg = (uint*)gs;
    for (int i = t; i < 512; i += 256) {
        int row = i >> 3;
        if (n0 + row < N)
            *(uint4*)(gsg + (size_t)(n0 + row) * 32 + (i & 7) * 4) =
                *(const uint4*)(&sbuf[i * 4]);
    }
}

// out[d] = dis[d]*(sum_e gs[s] + gs[d]) + b2.  2 nodes per wave (32-lane
// halves); 4 groups x 8 lanes per half; 4 edges/round (matches pad-4).
// 4-deep batched gathers + self-row prefetch.
__global__ void agg2_kernel(const uint* __restrict__ gs, const int* __restrict__ ssrc,
                            const int* __restrict__ offsets, const int* __restrict__ deg_e,
                            const float* __restrict__ dis, const float* __restrict__ b2,
                            float* __restrict__ out, int N) {
    int lane = threadIdx.x & 63;
    int half = lane >> 5;
    int hl = lane & 31;
    int grp = hl >> 3;
    int ck = hl & 7;
    int n = blockIdx.x * 8 + ((threadIdx.x >> 6) << 1) + half;
    if (n >= N) return;
    float acc[8];
#pragma unroll
    for (int i = 0; i < 8; i++) acc[i] = 0.f;
    int start = offsets[n], cnt = deg_e[n];  // cnt % 4 == 0
    uint4 uself = *(const uint4*)(gs + ((size_t)n << 5) + (ck << 2));  // prefetch self
    int hbase = half << 5;
    for (int base = 0; base < cnt; base += 32) {
        int m = min(32, cnt - base);
        int idx = base + hl;
        int sv = ssrc[start + (idx < cnt ? idx : cnt - 1)];
        int rounds = m >> 2;  // 1..8
        int q = 0;
        for (; q + 4 <= rounds; q += 4) {
            int sA = __shfl(sv, hbase | ((q + 0) << 2) | grp);
            int sB = __shfl(sv, hbase | ((q + 1) << 2) | grp);
            int sC = __shfl(sv, hbase | ((q + 2) << 2) | grp);
            int sD = __shfl(sv, hbase | ((q + 3) << 2) | grp);
            uint4 uA = *(const uint4*)(gs + ((size_t)sA << 5) + (ck << 2));
            uint4 uB = *(const uint4*)(gs + ((size_t)sB << 5) + (ck << 2));
            uint4 uC = *(const uint4*)(gs + ((size_t)sC << 5) + (ck << 2));
            uint4 uD = *(const uint4*)(gs + ((size_t)sD << 5) + (ck << 2));
            ACC8(uA); ACC8(uB); ACC8(uC); ACC8(uD);
        }
        for (; q + 2 <= rounds; q += 2) {
            int sA = __shfl(sv, hbase | ((q + 0) << 2) | grp);
            int sB = __shfl(sv, hbase | ((q + 1) << 2) | grp);
            uint4 uA = *(const uint4*)(gs + ((size_t)sA << 5) + (ck << 2));
            uint4 uB = *(const uint4*)(gs + ((size_t)sB << 5) + (ck << 2));
            ACC8(uA); ACC8(uB);
        }
        for (; q < rounds; q++) {
            int s = __shfl(sv, hbase | (q << 2) | grp);
            uint4 u = *(const uint4*)(gs + ((size_t)s << 5) + (ck << 2));
            ACC8(u);
        }
    }
#pragma unroll
    for (int i = 0; i < 8; i++) acc[i] += __shfl_down(acc[i], 16);
#pragma unroll
    for (int i = 0; i < 8; i++) acc[i] += __shfl_down(acc[i], 8);
    if (grp == 0) {
        ACC8(uself);  // self-loop term
        float dn = dis[n];
        float4 bb0 = *(const float4*)(b2 + ck * 8);
        float4 bb1 = *(const float4*)(b2 + ck * 8 + 4);
        float* op = out + (size_t)n * OUT_F + ck * 8;
        *(float4*)op = make_float4(fmaf(dn, acc[0], bb0.x), fmaf(dn, acc[1], bb0.y),
                                   fmaf(dn, acc[2], bb0.z), fmaf(dn, acc[3], bb0.w));
        *(float4*)(op + 4) = make_float4(fmaf(dn, acc[4], bb1.x), fmaf(dn, acc[5], bb1.y),
                                         fmaf(dn, acc[6], bb1.z), fmaf(dn, acc[7], bb1.w));
    }
}

extern "C" void kernel_launch(void* const* d_in, const int* in_sizes, int n_in,
                              void* d_out, int out_size, void* d_ws, size_t ws_size,
                              hipStream_t stream) {
    const float* x      = (const float*)d_in[0];
    const int*   edges  = (const int*)d_in[1];
    const float* W1     = (const float*)d_in[2];
    const float* b1     = (const float*)d_in[3];
    const float* gamma1 = (const float*)d_in[4];
    const float* beta1  = (const float*)d_in[5];
    const float* W2     = (const float*)d_in[6];
    const float* b2     = (const float*)d_in[7];
    float* out = (float*)d_out;

    int N = in_sizes[0] / IN_F;
    int E = in_sizes[1] / 2;
    const int* src = edges;
    const int* dst = edges + E;
    int NB = (N + BK_SIZE - 1) / BK_SIZE;   // 391
    int nchunks = (E + CHUNK - 1) / CHUNK;
    int nblk1 = (N + 63) / 64;

    char* ws = (char*)d_ws;
    size_t off = 0;
    auto alloc = [&](size_t bytes) -> void* {
        void* p = ws + off;
        off += (bytes + 255) & ~(size_t)255;
        return p;
    };
    int*    deg_e   = (int*)alloc((size_t)N * 4);
    int*    offsets = (int*)alloc((size_t)N * 4);
    float*  dis     = (float*)alloc((size_t)(N + 1) * 4);
    int*    bcursor = (int*)alloc(512 * 4);     // adjacent to bnsum: one memset
    float*  bnsum   = (float*)alloc(512 * 4);   // sums | sumsq
    int*    ssrc    = (int*)alloc((size_t)NB * (CAP + 768) * 4);  // padded CSR
    uint*   ebuf    = (uint*)alloc((size_t)NB * CAP * 4);
    uint*   xs      = (uint*)alloc((size_t)(N + 1) * (IN_F / 2) * 4); // +sentinel row
    uint*   zb      = (uint*)alloc((size_t)N * (IN_F / 2) * 4);
    ushort* out1b   = (ushort*)alloc((size_t)N * HID_F * 2);
    float*  bnp     = (float*)alloc((size_t)nblk1 * 512 * 4);         // block partials
    ushort* W1bp    = (ushort*)alloc(4 * 256 * 32 * 2);
    ushort* W2bp    = (ushort*)alloc(8 * 64 * 32 * 2);
    ushort* gs      = (ushort*)zb;  // alias: zb dead after gemm1; (N+1) rows x 64 bf16

    hipMemsetAsync(bcursor, 0, 2 * 512 * 4, stream);  // bcursor + bnsum

    scatter_wprep_kernel<<<nchunks + 96, 512, 0, stream>>>(src, dst, bcursor, ebuf,
                                                           W1, W2, W1bp, W2bp,
                                                           E, NB, nchunks);
    bucket_build_kernel<<<NB, 1024, 0, stream>>>(ebuf, bcursor, deg_e, offsets, dis, ssrc,
                                                 x, xs, N);
    {
        int noct = (N + 7) >> 3;                  // 12500 node octets
        int h0 = ((noct / 2 + 3) >> 2) << 2;      // 6252 (multiple of 4)
        int h1 = noct - h0;                       // 6248
        int grid0 = (h0 >> 2) << 3;               // 2 feature halves x 4 octets / 8 blocks
        int grid1 = ((h1 + 3) >> 2) << 3;
        aggx_kernel<<<grid0, 256, 0, stream>>>(xs, ssrc, offsets, deg_e, dis, zb, 0, N);
        aggx_kernel<<<grid1, 256, 0, stream>>>(xs, ssrc, offsets, deg_e, dis, zb, h0, N);
    }
    gemm1_kernel<<<nblk1, 256, 0, stream>>>(zb, (const uint*)W1bp, b1, out1b, bnp, N);
    bnred_kernel<<<32, 256, 0, stream>>>(bnp, bnsum, nblk1);
    gemm2_kernel<<<nblk1, 256, 0, stream>>>(out1b, (const uint*)W2bp, dis, bnsum,
                                            gamma1, beta1, gs, N);
    agg2_kernel<<<(N + 7) / 8, 256, 0, stream>>>((const uint*)gs, ssrc, offsets, deg_e, dis,
                                                 b2, out, N);
}